// Round 12
// baseline (451.947 us; speedup 1.0000x reference)
//
#include <hip/hip_runtime.h>

#define T_SEQ 2048

typedef __attribute__((ext_vector_type(8))) short short8;
typedef __attribute__((ext_vector_type(4))) float f32x4;

__device__ __forceinline__ unsigned short f32_to_bf16(float f){
  unsigned int u = __float_as_uint(f);
  u += 0x7fffu + ((u>>16)&1u);
  return (unsigned short)(u>>16);
}
__device__ __forceinline__ float bf16_to_f32(unsigned short h){
  unsigned int u = ((unsigned int)h) << 16;
  return __uint_as_float(u);
}

// async global->LDS, 16B per lane. LDS dest = wave-uniform base + lane*16.
__device__ __forceinline__ void g2l16(const void* g, void* l){
  __builtin_amdgcn_global_load_lds(
      (const __attribute__((address_space(1))) void*)g,
      (__attribute__((address_space(3))) void*)l, 16, 0, 0);
}

// call-free exact-GELU: Abramowitz-Stegun 7.1.26 erf, |eps|<=1.5e-7
__device__ __forceinline__ float gelu_exact(float v){
  float s = v * 0.70710678118f;
  float a = fabsf(s);
  float t = __builtin_amdgcn_rcpf(1.f + 0.3275911f*a);
  float p = t*(0.254829592f + t*(-0.284496736f + t*(1.421413741f +
            t*(-1.453152027f + t*1.061405429f))));
  float erf_a = 1.f - p*__expf(-a*a);
  float erf_s = (s < 0.f) ? -erf_a : erf_a;
  return 0.5f*v*(1.f + erf_s);
}

// --------------------------------------------- fused BigBird sparsity prep
__global__ __launch_bounds__(256) void build_sparse(const unsigned char* __restrict__ mraw,
                                                    int* __restrict__ cols,
                                                    int* __restrict__ ncols,
                                                    unsigned int* __restrict__ rmask){
  __shared__ unsigned int lmb[64][64];     // packed mask bits for this q-tile
  __shared__ int sCols[2048];
  __shared__ int sTotal;
  int qt = blockIdx.x, tid = threadIdx.x;
  bool is_byte = (mraw[2049] == 1);        // byte-bool vs 4-byte storage
  for (int e = tid; e < 64*64; e += 256){
    int r = e >> 6, wc = e & 63;
    unsigned int bits = 0u;
    if (is_byte){
      const unsigned char* p = mraw + (size_t)(qt*64+r)*T_SEQ + wc*32;
      #pragma unroll
      for (int j=0;j<32;j++) bits |= (p[j] ? 1u:0u) << j;
    } else {
      const int* p = (const int*)mraw + (size_t)(qt*64+r)*T_SEQ + wc*32;
      #pragma unroll
      for (int j=0;j<32;j++) bits |= (p[j] != 0 ? 1u:0u) << j;
    }
    lmb[r][wc] = bits;
  }
  __syncthreads();
  if (tid < 64){                           // wave 0: column-union scan
    int lane = tid;
    unsigned int w = 0;
    int rmaxr = (qt == 31) ? 63 : 64;      // exclude dense row T-1
    for (int r=0;r<rmaxr;r++) w |= lmb[r][lane];
    int pc = __popc(w);
    int inc = pc;
    #pragma unroll
    for (int d=1; d<64; d<<=1){ int t = __shfl_up(inc,d,64); if (lane>=d) inc += t; }
    int total = __shfl(inc, 63, 64);
    int idx = inc - pc;
    unsigned int ww = w;
    while (ww){ int b=__ffs(ww)-1; ww&=ww-1; int c=lane*32+b;
                sCols[idx]=c; cols[qt*2048+idx]=c; idx++; }
    for (int j = total + lane; j < 2048; j += 64){ sCols[j] = -1; cols[qt*2048+j] = -1; }
    if (lane==0){ int nc = (total+63)&~63; ncols[qt]=nc; sTotal=nc; }
  }
  __syncthreads();
  int nw = sTotal >> 5;
  for (int e = tid; e < 64*nw; e += 256){
    int row = e / nw, wj = e % nw;
    unsigned int bits = 0;
    #pragma unroll
    for (int b=0;b<32;b++){
      int c = sCols[wj*32+b];
      if (c >= 0) bits |= ((lmb[row][c>>5] >> (c&31)) & 1u) << b;
    }
    rmask[(size_t)(qt*64+row)*64 + wj] = bits;
  }
}

// --------------------------------- fused weight transpose+convert (1 launch)
__global__ __launch_bounds__(256) void transcvt_all(const float* __restrict__ Wq,
                                                    const float* __restrict__ Wk,
                                                    const float* __restrict__ Wv,
                                                    const float* __restrict__ Wo,
                                                    const float* __restrict__ W1,
                                                    const float* __restrict__ W2,
                                                    unsigned short* __restrict__ wqkvT,
                                                    unsigned short* __restrict__ woT,
                                                    unsigned short* __restrict__ w1T,
                                                    unsigned short* __restrict__ w2T){
  __shared__ float tile[32][33];
  int bid = blockIdx.x;
  const float* W; unsigned short* WT; int K, N, t;
  if (bid < 4096){
    int which = bid >> 10; t = bid & 1023; K = 1024; N = 1024;
    if (which==0){ W=Wq; WT=wqkvT; }
    else if (which==1){ W=Wk; WT=wqkvT+1024*1024; }
    else if (which==2){ W=Wv; WT=wqkvT+2*1024*1024; }
    else { W=Wo; WT=woT; }
  } else if (bid < 8192){ t = bid-4096; K=1024; N=4096; W=W1; WT=w1T; }
  else { t = bid-8192; K=4096; N=1024; W=W2; WT=w2T; }
  int ntn = N >> 5;
  int tn = t % ntn, tk = t / ntn;
  int tx = threadIdx.x & 31, ty = threadIdx.x >> 5;
  int n0 = tn*32, k0 = tk*32;
  #pragma unroll
  for (int j=0;j<32;j+=8)
    tile[ty+j][tx] = W[(size_t)(k0+ty+j)*N + n0 + tx];
  __syncthreads();
  #pragma unroll
  for (int j=0;j<32;j+=8)
    WT[(size_t)(n0+ty+j)*K + k0 + tx] = f32_to_bf16(tile[tx][ty+j]);
}

// ---------------------------------------------------------------- layernorm
__global__ __launch_bounds__(256) void ln_kernel(const float* __restrict__ x,
                                                 const float* __restrict__ g,
                                                 const float* __restrict__ b,
                                                 unsigned short* __restrict__ out){
  int row = blockIdx.x, tid = threadIdx.x;
  const float* xr = x + (size_t)row*1024;
  float4 xv = *(const float4*)(xr + tid*4);
  float s  = xv.x+xv.y+xv.z+xv.w;
  float s2 = xv.x*xv.x + xv.y*xv.y + xv.z*xv.z + xv.w*xv.w;
  #pragma unroll
  for (int d=1; d<64; d<<=1){ s += __shfl_xor(s,d,64); s2 += __shfl_xor(s2,d,64); }
  __shared__ float ls[4], ls2[4];
  int wid = tid >> 6;
  if ((tid & 63) == 0){ ls[wid]=s; ls2[wid]=s2; }
  __syncthreads();
  float tot = ls[0]+ls[1]+ls[2]+ls[3];
  float tot2= ls2[0]+ls2[1]+ls2[2]+ls2[3];
  float mu  = tot * (1.f/1024.f);
  float var = tot2 * (1.f/1024.f) - mu*mu;
  float inv = rsqrtf(var + 1e-5f);
  float4 gv = *(const float4*)(g + tid*4);
  float4 bv = *(const float4*)(b + tid*4);
  unsigned short o0 = f32_to_bf16((xv.x-mu)*inv*gv.x + bv.x);
  unsigned short o1 = f32_to_bf16((xv.y-mu)*inv*gv.y + bv.y);
  unsigned short o2 = f32_to_bf16((xv.z-mu)*inv*gv.z + bv.z);
  unsigned short o3 = f32_to_bf16((xv.w-mu)*inv*gv.w + bv.w);
  unsigned short* op = out + (size_t)row*1024 + tid*4;
  op[0]=o0; op[1]=o1; op[2]=o2; op[3]=o3;
}

// ------------------------------------------------------------------- GEMM
// 128x128 tile, BK=64. A staged in LDS (global_load_lds, 3-bit XOR swizzle);
// B fragments loaded DIRECTLY global->VGPR (b128 gathers, 64B-contiguous per
// row in B^T layout) — halves LDS-pipe traffic and runs it concurrently with
// the L1/global path. B loads issued before the barrier so they fly during
// the A-stage drain.
template<bool GELU, bool BIAS, bool RES, bool OUTBF>
__global__ __launch_bounds__(256,4) void gemm_bt(const unsigned short* __restrict__ A,
                                                 const unsigned short* __restrict__ BT,
                                                 void* __restrict__ Cout,
                                                 const float* __restrict__ bias,
                                                 const float* __restrict__ res,
                                                 int M, int N, int K){
  __shared__ unsigned short sA[128*64];
  int tid = threadIdx.x;
  int m0 = blockIdx.x*128, n0 = blockIdx.y*128;
  int wid = tid>>6, lane = tid&63;
  int wm = (wid>>1)*64, wn = (wid&1)*64;
  int l16 = lane&15, quad = lane>>4;
  int qa0 = (quad     ^ (l16&7))*8;
  int qa1 = ((quad+4) ^ (l16&7))*8;
  const unsigned short* bptr = BT + (size_t)(n0+wn+l16)*K + quad*8;

  f32x4 acc[4][4] = {};
  for (int k0=0; k0<K; k0+=64){
    // B fragments for both k-slices: direct global->VGPR
    short8 bf[2][4];
    #pragma unroll
    for (int kk=0;kk<2;kk++)
      #pragma unroll
      for (int ni=0;ni<4;ni++)
        bf[kk][ni] = *(const short8*)(bptr + (size_t)(ni*16)*K + k0 + kk*32);
    // A tile -> LDS
    #pragma unroll
    for (int i=0;i<4;i++){
      int t = i*256 + tid;                         // [0,1024)
      int row = t>>3;
      int kc = ((t&7) ^ (row&7))*8;
      int wb = i*256 + (tid & ~63);
      g2l16(A + (size_t)(m0+row)*K + k0 + kc, sA + wb*8);
    }
    __syncthreads();
    #pragma unroll
    for (int kk=0;kk<2;kk++){
      int qa = kk ? qa1 : qa0;
      short8 af[4];
      #pragma unroll
      for (int mi=0;mi<4;mi++) af[mi] = *(const short8*)(sA + (wm+mi*16+l16)*64 + qa);
      #pragma unroll
      for (int mi=0;mi<4;mi++)
        #pragma unroll
        for (int ni=0;ni<4;ni++)
          acc[mi][ni] = __builtin_amdgcn_mfma_f32_16x16x32_bf16(af[mi], bf[kk][ni], acc[mi][ni], 0,0,0);
    }
    __syncthreads();
  }
  #pragma unroll
  for (int mi=0;mi<4;mi++)
    #pragma unroll
    for (int ni=0;ni<4;ni++){
      int col = n0 + wn + ni*16 + l16;
      float bval = 0.f;
      if constexpr (BIAS) bval = bias[col];
      #pragma unroll
      for (int r=0;r<4;r++){
        int row = m0 + wm + mi*16 + quad*4 + r;
        float v = acc[mi][ni][r] + bval;
        if constexpr (GELU) v = gelu_exact(v);
        if constexpr (RES)  v += res[(size_t)row*N + col];
        if constexpr (OUTBF) ((unsigned short*)Cout)[(size_t)row*N + col] = f32_to_bf16(v);
        else                 ((float*)Cout)[(size_t)row*N + col] = v;
      }
    }
}

// 128x64-tile, BK=64, A-LDS + B-direct (512 blocks -> 2/CU for N=1024).
template<bool BIAS, bool RES, bool OUTBF>
__global__ __launch_bounds__(256,2) void gemm_bt_n64(const unsigned short* __restrict__ A,
                                                     const unsigned short* __restrict__ BT,
                                                     void* __restrict__ Cout,
                                                     const float* __restrict__ bias,
                                                     const float* __restrict__ res,
                                                     int M, int N, int K){
  __shared__ unsigned short sA[128*64];
  int tid = threadIdx.x;
  int m0 = blockIdx.x*128, n0 = blockIdx.y*64;
  int wid = tid>>6, lane = tid&63;
  int wm = (wid>>1)*64, wn = (wid&1)*32;
  int l16 = lane&15, quad = lane>>4;
  int qa0 = (quad     ^ (l16&7))*8;
  int qa1 = ((quad+4) ^ (l16&7))*8;
  const unsigned short* bptr = BT + (size_t)(n0+wn+l16)*K + quad*8;

  f32x4 acc[4][2] = {};
  for (int k0=0; k0<K; k0+=64){
    short8 bf[2][2];
    #pragma unroll
    for (int kk=0;kk<2;kk++)
      #pragma unroll
      for (int ni=0;ni<2;ni++)
        bf[kk][ni] = *(const short8*)(bptr + (size_t)(ni*16)*K + k0 + kk*32);
    #pragma unroll
    for (int i=0;i<4;i++){
      int t = i*256 + tid;                         // [0,1024)
      int row = t>>3;
      int kc = ((t&7) ^ (row&7))*8;
      int wb = i*256 + (tid & ~63);
      g2l16(A + (size_t)(m0+row)*K + k0 + kc, sA + wb*8);
    }
    __syncthreads();
    #pragma unroll
    for (int kk=0;kk<2;kk++){
      int qa = kk ? qa1 : qa0;
      short8 af[4];
      #pragma unroll
      for (int mi=0;mi<4;mi++) af[mi] = *(const short8*)(sA + (wm+mi*16+l16)*64 + qa);
      #pragma unroll
      for (int mi=0;mi<4;mi++)
        #pragma unroll
        for (int ni=0;ni<2;ni++)
          acc[mi][ni] = __builtin_amdgcn_mfma_f32_16x16x32_bf16(af[mi], bf[kk][ni], acc[mi][ni], 0,0,0);
    }
    __syncthreads();
  }
  #pragma unroll
  for (int mi=0;mi<4;mi++)
    #pragma unroll
    for (int ni=0;ni<2;ni++){
      int col = n0 + wn + ni*16 + l16;
      float bval = 0.f;
      if constexpr (BIAS) bval = bias[col];
      #pragma unroll
      for (int r=0;r<4;r++){
        int row = m0 + wm + mi*16 + quad*4 + r;
        float v = acc[mi][ni][r] + bval;
        if constexpr (RES)  v += res[(size_t)row*N + col];
        if constexpr (OUTBF) ((unsigned short*)Cout)[(size_t)row*N + col] = f32_to_bf16(v);
        else                 ((float*)Cout)[(size_t)row*N + col] = v;
      }
    }
}

// ------------------------------------------------------------- attention
// grid (33, 32): x<32 -> sparse-gather flash attention for q-tile 31-x;
// x==32 -> dense last-row (row T-1) attention, vectorized two-pass softmax.
__global__ __launch_bounds__(256,4) void attn_kernel(const unsigned short* __restrict__ qkv,
                                                     const int* __restrict__ cols,
                                                     const int* __restrict__ ncols,
                                                     const unsigned int* __restrict__ rmask,
                                                     unsigned short* __restrict__ out){
  __shared__ __align__(16) char smem[36864];
  int bh = blockIdx.y;                // 0..31
  int b = bh >> 4, h = bh & 15;
  int tid = threadIdx.x, wid = tid>>6, lane = tid&63;
  const int RS = 3072;
  const size_t base = (size_t)b * T_SEQ * RS;

  if (blockIdx.x == 32){
    // ---------------- dense last row ----------------
    float* sS  = (float*)smem;                      // 2048 f32
    float* sOr = (float*)(smem + 8192);             // 32 x 65 f32 (padded)
    float* sRed= (float*)(smem + 16512);            // 8 f32
    unsigned short* sQ = (unsigned short*)(smem + 16544); // 64 bf16

    if (tid < 8)
      ((uint4*)sQ)[tid] = *(const uint4*)(qkv + base + (size_t)(T_SEQ-1)*RS + h*64 + tid*8);
    __syncthreads();
    unsigned short q16[64];
    #pragma unroll
    for (int c=0;c<8;c++) *(uint4*)(q16 + c*8) = ((const uint4*)sQ)[c];

    float lmax = -1e30f;
    #pragma unroll
    for (int i=0;i<8;i++){
      int k = tid + 256*i;
      const unsigned short* kp = qkv + base + (size_t)k*RS + 1024 + h*64;
      float acc = 0.f;
      #pragma unroll
      for (int c=0;c<8;c++){
        unsigned short kk[8];
        *(uint4*)kk = *(const uint4*)(kp + c*8);
        #pragma unroll
        for (int j=0;j<8;j++) acc += bf16_to_f32(q16[c*8+j])*bf16_to_f32(kk[j]);
      }
      float sv = acc * 0.125f;
      sS[k] = sv;
      lmax = fmaxf(lmax, sv);
    }
    #pragma unroll
    for (int d=1; d<64; d<<=1) lmax = fmaxf(lmax, __shfl_xor(lmax, d, 64));
    if (lane == 0) sRed[wid] = lmax;
    __syncthreads();
    float m = fmaxf(fmaxf(sRed[0],sRed[1]), fmaxf(sRed[2],sRed[3]));
    float lsum = 0.f;
    #pragma unroll
    for (int i=0;i<8;i++){
      int k = tid + 256*i;
      float p = __expf(sS[k] - m);
      sS[k] = p;
      lsum += p;
    }
    #pragma unroll
    for (int d=1; d<64; d<<=1) lsum += __shfl_xor(lsum, d, 64);
    if (lane == 0) sRed[4+wid] = lsum;
    __syncthreads();
    float l = sRed[4]+sRed[5]+sRed[6]+sRed[7];

    int dg = tid & 7, kl = tid >> 3;
    float o8[8] = {};
    const unsigned short* vbase = qkv + base + 2048 + h*64 + dg*8;
    #pragma unroll 4
    for (int i=0;i<64;i++){
      int k = kl + 32*i;
      float p = sS[k];
      unsigned short vv[8];
      *(uint4*)vv = *(const uint4*)(vbase + (size_t)k*RS);
      #pragma unroll
      for (int j=0;j<8;j++) o8[j] += p * bf16_to_f32(vv[j]);
    }
    #pragma unroll
    for (int j=0;j<8;j++) sOr[kl*65 + dg*8 + j] = o8[j];
    __syncthreads();
    if (tid < 64){
      float s = 0.f;
      #pragma unroll
      for (int k2=0;k2<32;k2++) s += sOr[k2*65 + tid];
      out[(size_t)(b*T_SEQ + T_SEQ-1)*1024 + h*64 + tid] = f32_to_bf16(s / l);
    }
    return;
  }

  // ---------------- sparse q-tiles ----------------
  unsigned short* sK  = (unsigned short*)smem;            // [64][72]
  unsigned short* sVt = (unsigned short*)(smem +  9216);  // [64][72]
  unsigned short* sX  = (unsigned short*)(smem + 18432);  // [64][72]
  unsigned short* sP  = (unsigned short*)(smem + 27648);  // [4][16][72]

  int qt = 31 - blockIdx.x;
  int l16 = lane&15, quad = lane>>4;
  int q0 = qt*64;

  const int* gcols = cols + qt*2048;
  int niter = ncols[qt] >> 6;

  int qrow = q0 + wid*16 + l16;
  const unsigned short* qptr = qkv + base + (size_t)qrow*RS + h*64;
  short8 qf0 = *(const short8*)(qptr + quad*8);
  short8 qf1 = *(const short8*)(qptr + 32 + quad*8);

  f32x4 o[4] = {};
  float m_i[4], l_i[4];
  #pragma unroll
  for (int r=0;r<4;r++){ m_i[r] = -1e30f; l_i[r] = 0.f; }

  int krow0 = tid>>3, krow1 = 32 + (tid>>3), dc = (tid&7)*8;
  int c0n = gcols[krow0], c1n = gcols[krow1];

  for (int kt=0; kt<niter; ++kt){
    int c0 = c0n < 0 ? 0 : c0n;
    int c1 = c1n < 0 ? 0 : c1n;
    const unsigned short* p0 = qkv + base + (size_t)c0*RS + 1024 + h*64 + dc;
    const unsigned short* p1 = qkv + base + (size_t)c1*RS + 1024 + h*64 + dc;
    uint4 k0 = *(const uint4*)p0;
    uint4 k1 = *(const uint4*)p1;
    uint4 v0 = *(const uint4*)(p0 + 1024);
    uint4 v1 = *(const uint4*)(p1 + 1024);
    if (kt+1 < niter){
      c0n = gcols[(kt+1)*64 + krow0];
      c1n = gcols[(kt+1)*64 + krow1];
    }
    __syncthreads();                       // prev iter's LDS readers done
    *(uint4*)(sK + krow0*72 + dc) = k0;
    *(uint4*)(sK + krow1*72 + dc) = k1;
    *(uint4*)(sX + krow0*72 + dc) = v0;
    *(uint4*)(sX + krow1*72 + dc) = v1;
    __syncthreads();                       // sK/sX visible

    // transpose sX -> sVt (krow lane-fast => conflict-free)
    #pragma unroll
    for (int pass=0; pass<2; ++pass){
      int dg = pass*4 + wid;
      unsigned short v8[8];
      *(uint4*)v8 = *(const uint4*)(sX + lane*72 + dg*8);
      #pragma unroll
      for (int j=0;j<8;j++) sVt[(dg*8+j)*72 + lane] = v8[j];
    }

    // S = Q @ K^T
    f32x4 s[4];
    #pragma unroll
    for (int nt=0;nt<4;nt++){
      f32x4 z = {};
      short8 kb0 = *(const short8*)(sK + (nt*16+l16)*72 + quad*8);
      short8 kb1 = *(const short8*)(sK + (nt*16+l16)*72 + 32 + quad*8);
      z = __builtin_amdgcn_mfma_f32_16x16x32_bf16(qf0, kb0, z, 0,0,0);
      z = __builtin_amdgcn_mfma_f32_16x16x32_bf16(qf1, kb1, z, 0,0,0);
      s[nt] = z;
    }

    // mask (remapped bits) + scale
    float rowmax[4];
    #pragma unroll
    for (int r=0;r<4;r++){
      int rowin = wid*16 + quad*4 + r;
      const unsigned int* mrow = rmask + (size_t)(qt*64+rowin)*64 + kt*2;
      unsigned long long m64 = (unsigned long long)mrow[0] |
                               ((unsigned long long)mrow[1] << 32);
      float rm = -1e30f;
      #pragma unroll
      for (int nt=0;nt<4;nt++){
        int c6 = nt*16 + l16;
        bool ok = (m64 >> c6) & 1ull;
        float v = ok ? s[nt][r]*0.125f : -1e30f;
        s[nt][r] = v;
        rm = fmaxf(rm, v);
      }
      rowmax[r] = rm;
    }
    #pragma unroll
    for (int r=0;r<4;r++){
      float v = rowmax[r];
      #pragma unroll
      for (int d=1; d<16; d<<=1) v = fmaxf(v, __shfl_xor(v,d,64));
      rowmax[r] = v;
    }
    float alpha[4];
    #pragma unroll
    for (int r=0;r<4;r++){
      float mnew = fmaxf(m_i[r], rowmax[r]);
      alpha[r] = __expf(m_i[r] - mnew);
      m_i[r] = mnew;
    }
    #pragma unroll
    for (int nt=0;nt<4;nt++)
      #pragma unroll
      for (int r=0;r<4;r++)
        s[nt][r] = __expf(s[nt][r] - m_i[r]);
    #pragma unroll
    for (int r=0;r<4;r++){
      float v = s[0][r]+s[1][r]+s[2][r]+s[3][r];
      #pragma unroll
      for (int d=1; d<16; d<<=1) v += __shfl_xor(v,d,64);
      l_i[r] = l_i[r]*alpha[r] + v;
    }
    // P: C-layout -> per-wave LDS -> A-layout (same-wave RAW, no barrier)
    unsigned short* sPw = sP + wid*16*72;
    #pragma unroll
    for (int nt=0;nt<4;nt++)
      #pragma unroll
      for (int r=0;r<4;r++)
        sPw[(quad*4+r)*72 + nt*16 + l16] = f32_to_bf16(s[nt][r]);
    short8 p0f = *(const short8*)(sPw + l16*72 + quad*8);
    short8 p1f = *(const short8*)(sPw + l16*72 + 32 + quad*8);
    #pragma unroll
    for (int nt=0;nt<4;nt++)
      #pragma unroll
      for (int r=0;r<4;r++)
        o[nt][r] *= alpha[r];
    __syncthreads();                       // sVt complete
    #pragma unroll
    for (int nt=0;nt<4;nt++){
      short8 vb0 = *(const short8*)(sVt + (nt*16+l16)*72 + quad*8);
      short8 vb1 = *(const short8*)(sVt + (nt*16+l16)*72 + 32 + quad*8);
      o[nt] = __builtin_amdgcn_mfma_f32_16x16x32_bf16(p0f, vb0, o[nt], 0,0,0);
      o[nt] = __builtin_amdgcn_mfma_f32_16x16x32_bf16(p1f, vb1, o[nt], 0,0,0);
    }
  }
  #pragma unroll
  for (int nt=0;nt<4;nt++)
    #pragma unroll
    for (int r=0;r<4;r++){
      int row = q0 + wid*16 + quad*4 + r;
      if (row == T_SEQ-1) continue;        // owned by lastrow block (race!)
      int col = h*64 + nt*16 + l16;
      out[(size_t)(b*T_SEQ + row)*1024 + col] = f32_to_bf16(o[nt][r] / l_i[r]);
    }
}

// ---------------------------------------------------------------- launch
extern "C" void kernel_launch(void* const* d_in, const int* in_sizes, int n_in,
                              void* d_out, int out_size, void* d_ws, size_t ws_size,
                              hipStream_t stream) {
  const float* x     = (const float*)d_in[0];
  const unsigned char* mask = (const unsigned char*)d_in[1];
  const float* ln1_g = (const float*)d_in[2];
  const float* ln1_b = (const float*)d_in[3];
  const float* ln2_g = (const float*)d_in[4];
  const float* ln2_b = (const float*)d_in[5];
  const float* Wq = (const float*)d_in[6];
  const float* Wk = (const float*)d_in[7];
  const float* Wv = (const float*)d_in[8];
  const float* Wo = (const float*)d_in[9];
  const float* bo = (const float*)d_in[10];
  const float* W1 = (const float*)d_in[11];
  const float* b1 = (const float*)d_in[12];
  const float* W2 = (const float*)d_in[13];
  const float* b2 = (const float*)d_in[14];
  float* out = (float*)d_out;

  char* ws = (char*)d_ws;
  unsigned short* wqkvT = (unsigned short*)(ws);              // 3072x1024 bf16
  unsigned short* woT   = (unsigned short*)(ws + 6291456);    // 1024x1024
  unsigned short* w1T   = (unsigned short*)(ws + 8388608);    // 4096x1024
  unsigned short* w2T   = (unsigned short*)(ws + 16777216);   // 1024x4096
  unsigned short* h_bf  = (unsigned short*)(ws + 25165824);   // 4096x1024 (reused as h2)
  unsigned short* qkv   = (unsigned short*)(ws + 33554432);   // 4096x3072
  unsigned short* aout  = (unsigned short*)(ws + 58720256);   // 4096x1024
  int*            cols  = (int*)(ws + 67108864);              // 32x2048 ints (256 KB)
  int*            ncols = (int*)(ws + 67371008);              // 32 ints
  unsigned int*   rmask = (unsigned int*)(ws + 67371136);     // 32x64x64 words (512 KB)
  unsigned short* ff1   = qkv;                                // reuse: 4096x4096

  build_sparse<<<32,256,0,stream>>>(mask, cols, ncols, rmask);
  transcvt_all<<<12288,256,0,stream>>>(Wq, Wk, Wv, Wo, W1, W2, wqkvT, woT, w1T, w2T);

  ln_kernel<<<4096,256,0,stream>>>(x, ln1_g, ln1_b, h_bf);
  gemm_bt<false,false,false,true><<<dim3(32,24),256,0,stream>>>(h_bf, wqkvT, qkv, nullptr, nullptr, 4096, 3072, 1024);
  attn_kernel<<<dim3(33,32),256,0,stream>>>(qkv, cols, ncols, rmask, aout);
  gemm_bt_n64<true,true,false><<<dim3(32,16),256,0,stream>>>(aout, woT, out, bo, x, 4096, 1024, 1024);
  ln_kernel<<<4096,256,0,stream>>>(out, ln2_g, ln2_b, h_bf);
  gemm_bt<true,true,false,true><<<dim3(32,32),256,0,stream>>>(h_bf, w1T, ff1, b1, nullptr, 4096, 4096, 1024);
  gemm_bt_n64<true,true,false><<<dim3(32,16),256,0,stream>>>(ff1, w2T, out, b2, out, 4096, 1024, 4096);
}

// Round 13
// 341.154 us; speedup vs baseline: 1.3248x; 1.3248x over previous
//
#include <hip/hip_runtime.h>

#define T_SEQ 2048

typedef __attribute__((ext_vector_type(8))) short short8;
typedef __attribute__((ext_vector_type(4))) float f32x4;

__device__ __forceinline__ unsigned short f32_to_bf16(float f){
  unsigned int u = __float_as_uint(f);
  u += 0x7fffu + ((u>>16)&1u);
  return (unsigned short)(u>>16);
}
__device__ __forceinline__ float bf16_to_f32(unsigned short h){
  unsigned int u = ((unsigned int)h) << 16;
  return __uint_as_float(u);
}

// async global->LDS, 16B per lane. LDS dest = wave-uniform base + lane*16.
__device__ __forceinline__ void g2l16(const void* g, void* l){
  __builtin_amdgcn_global_load_lds(
      (const __attribute__((address_space(1))) void*)g,
      (__attribute__((address_space(3))) void*)l, 16, 0, 0);
}

// call-free exact-GELU: Abramowitz-Stegun 7.1.26 erf, |eps|<=1.5e-7
__device__ __forceinline__ float gelu_exact(float v){
  float s = v * 0.70710678118f;
  float a = fabsf(s);
  float t = __builtin_amdgcn_rcpf(1.f + 0.3275911f*a);
  float p = t*(0.254829592f + t*(-0.284496736f + t*(1.421413741f +
            t*(-1.453152027f + t*1.061405429f))));
  float erf_a = 1.f - p*__expf(-a*a);
  float erf_s = (s < 0.f) ? -erf_a : erf_a;
  return 0.5f*v*(1.f + erf_s);
}

// ---------------------------------------------------------- fused prep
// blocks [0,32): BigBird sparsity lists; [32,12320): weight transpose+cvt;
// [12320,16416): LayerNorm1. All independent -> one dispatch.
__global__ __launch_bounds__(256) void prep_fused(const unsigned char* __restrict__ mraw,
                                                  int* __restrict__ cols,
                                                  int* __restrict__ ncols,
                                                  unsigned int* __restrict__ rmask,
                                                  const float* __restrict__ Wq,
                                                  const float* __restrict__ Wk,
                                                  const float* __restrict__ Wv,
                                                  const float* __restrict__ Wo,
                                                  const float* __restrict__ W1,
                                                  const float* __restrict__ W2,
                                                  unsigned short* __restrict__ wqkvT,
                                                  unsigned short* __restrict__ woT,
                                                  unsigned short* __restrict__ w1T,
                                                  unsigned short* __restrict__ w2T,
                                                  const float* __restrict__ x,
                                                  const float* __restrict__ ln1_g,
                                                  const float* __restrict__ ln1_b,
                                                  unsigned short* __restrict__ h_bf){
  __shared__ __align__(16) char smem[24832];
  int bid = blockIdx.x, tid = threadIdx.x;

  if (bid < 32){
    // ---------------- BigBird sparsity prep ----------------
    unsigned int (*lmb)[64] = (unsigned int(*)[64])smem;     // 16 KB
    int* sCols = (int*)(smem + 16384);                       // 8 KB
    int* sTotal = (int*)(smem + 24576);
    int qt = bid;
    bool is_byte = (mraw[2049] == 1);
    for (int e = tid; e < 64*64; e += 256){
      int r = e >> 6, wc = e & 63;
      unsigned int bits = 0u;
      if (is_byte){
        const unsigned char* p = mraw + (size_t)(qt*64+r)*T_SEQ + wc*32;
        #pragma unroll
        for (int j=0;j<32;j++) bits |= (p[j] ? 1u:0u) << j;
      } else {
        const int* p = (const int*)mraw + (size_t)(qt*64+r)*T_SEQ + wc*32;
        #pragma unroll
        for (int j=0;j<32;j++) bits |= (p[j] != 0 ? 1u:0u) << j;
      }
      lmb[r][wc] = bits;
    }
    __syncthreads();
    if (tid < 64){                         // wave 0: column-union scan
      int lane = tid;
      unsigned int w = 0;
      int rmaxr = (qt == 31) ? 63 : 64;    // exclude dense row T-1
      for (int r=0;r<rmaxr;r++) w |= lmb[r][lane];
      int pc = __popc(w);
      int inc = pc;
      #pragma unroll
      for (int d=1; d<64; d<<=1){ int t = __shfl_up(inc,d,64); if (lane>=d) inc += t; }
      int total = __shfl(inc, 63, 64);
      int idx = inc - pc;
      unsigned int ww = w;
      while (ww){ int b=__ffs(ww)-1; ww&=ww-1; int c=lane*32+b;
                  sCols[idx]=c; cols[qt*2048+idx]=c; idx++; }
      for (int j = total + lane; j < 2048; j += 64){ sCols[j] = -1; cols[qt*2048+j] = -1; }
      if (lane==0){ int nc = (total+63)&~63; ncols[qt]=nc; *sTotal=nc; }
    }
    __syncthreads();
    int nw = *sTotal >> 5;
    for (int e = tid; e < 64*nw; e += 256){
      int row = e / nw, wj = e % nw;
      unsigned int bits = 0;
      #pragma unroll
      for (int b=0;b<32;b++){
        int c = sCols[wj*32+b];
        if (c >= 0) bits |= ((lmb[row][c>>5] >> (c&31)) & 1u) << b;
      }
      rmask[(size_t)(qt*64+row)*64 + wj] = bits;
    }
    return;
  }

  if (bid < 12320){
    // ---------------- weight transpose+convert ----------------
    float (*tile)[33] = (float(*)[33])smem;                  // 4.2 KB
    int wbid = bid - 32;
    const float* W; unsigned short* WT; int K, N, t;
    if (wbid < 4096){
      int which = wbid >> 10; t = wbid & 1023; K = 1024; N = 1024;
      if (which==0){ W=Wq; WT=wqkvT; }
      else if (which==1){ W=Wk; WT=wqkvT+1024*1024; }
      else if (which==2){ W=Wv; WT=wqkvT+2*1024*1024; }
      else { W=Wo; WT=woT; }
    } else if (wbid < 8192){ t = wbid-4096; K=1024; N=4096; W=W1; WT=w1T; }
    else { t = wbid-8192; K=4096; N=1024; W=W2; WT=w2T; }
    int ntn = N >> 5;
    int tn = t % ntn, tk = t / ntn;
    int tx = tid & 31, ty = tid >> 5;
    int n0 = tn*32, k0 = tk*32;
    #pragma unroll
    for (int j=0;j<32;j+=8)
      tile[ty+j][tx] = W[(size_t)(k0+ty+j)*N + n0 + tx];
    __syncthreads();
    #pragma unroll
    for (int j=0;j<32;j+=8)
      WT[(size_t)(n0+ty+j)*K + k0 + tx] = f32_to_bf16(tile[tx][ty+j]);
    return;
  }

  // ---------------- LayerNorm 1 ----------------
  {
    float* ls  = (float*)smem;
    float* ls2 = (float*)(smem + 16);
    int row = bid - 12320;
    const float* xr = x + (size_t)row*1024;
    float4 xv = *(const float4*)(xr + tid*4);
    float s  = xv.x+xv.y+xv.z+xv.w;
    float s2 = xv.x*xv.x + xv.y*xv.y + xv.z*xv.z + xv.w*xv.w;
    #pragma unroll
    for (int d=1; d<64; d<<=1){ s += __shfl_xor(s,d,64); s2 += __shfl_xor(s2,d,64); }
    int wid = tid >> 6;
    if ((tid & 63) == 0){ ls[wid]=s; ls2[wid]=s2; }
    __syncthreads();
    float tot = ls[0]+ls[1]+ls[2]+ls[3];
    float tot2= ls2[0]+ls2[1]+ls2[2]+ls2[3];
    float mu  = tot * (1.f/1024.f);
    float var = tot2 * (1.f/1024.f) - mu*mu;
    float inv = rsqrtf(var + 1e-5f);
    float4 gv = *(const float4*)(ln1_g + tid*4);
    float4 bv = *(const float4*)(ln1_b + tid*4);
    unsigned short o0 = f32_to_bf16((xv.x-mu)*inv*gv.x + bv.x);
    unsigned short o1 = f32_to_bf16((xv.y-mu)*inv*gv.y + bv.y);
    unsigned short o2 = f32_to_bf16((xv.z-mu)*inv*gv.z + bv.z);
    unsigned short o3 = f32_to_bf16((xv.w-mu)*inv*gv.w + bv.w);
    unsigned short* op = h_bf + (size_t)row*1024 + tid*4;
    op[0]=o0; op[1]=o1; op[2]=o2; op[3]=o3;
  }
}

// ---------------------------------------------------------------- layernorm
__global__ __launch_bounds__(256) void ln_kernel(const float* __restrict__ x,
                                                 const float* __restrict__ g,
                                                 const float* __restrict__ b,
                                                 unsigned short* __restrict__ out){
  int row = blockIdx.x, tid = threadIdx.x;
  const float* xr = x + (size_t)row*1024;
  float4 xv = *(const float4*)(xr + tid*4);
  float s  = xv.x+xv.y+xv.z+xv.w;
  float s2 = xv.x*xv.x + xv.y*xv.y + xv.z*xv.z + xv.w*xv.w;
  #pragma unroll
  for (int d=1; d<64; d<<=1){ s += __shfl_xor(s,d,64); s2 += __shfl_xor(s2,d,64); }
  __shared__ float ls[4], ls2[4];
  int wid = tid >> 6;
  if ((tid & 63) == 0){ ls[wid]=s; ls2[wid]=s2; }
  __syncthreads();
  float tot = ls[0]+ls[1]+ls[2]+ls[3];
  float tot2= ls2[0]+ls2[1]+ls2[2]+ls2[3];
  float mu  = tot * (1.f/1024.f);
  float var = tot2 * (1.f/1024.f) - mu*mu;
  float inv = rsqrtf(var + 1e-5f);
  float4 gv = *(const float4*)(g + tid*4);
  float4 bv = *(const float4*)(b + tid*4);
  unsigned short o0 = f32_to_bf16((xv.x-mu)*inv*gv.x + bv.x);
  unsigned short o1 = f32_to_bf16((xv.y-mu)*inv*gv.y + bv.y);
  unsigned short o2 = f32_to_bf16((xv.z-mu)*inv*gv.z + bv.z);
  unsigned short o3 = f32_to_bf16((xv.w-mu)*inv*gv.w + bv.w);
  unsigned short* op = out + (size_t)row*1024 + tid*4;
  op[0]=o0; op[1]=o1; op[2]=o2; op[3]=o3;
}

// ------------------------------------------------------------------- GEMM
// 128x128 tile, BK=64, both operands via global_load_lds, 3-bit XOR swizzle.
// Single-buffered: dbuf/split-K/B-direct all measured slower (R9/R10/R12) —
// the barrier's vmcnt(0) drain is structural; this staging is the best found.
template<bool GELU, bool BIAS, bool RES, bool OUTBF>
__global__ __launch_bounds__(256,4) void gemm_bt(const unsigned short* __restrict__ A,
                                                 const unsigned short* __restrict__ BT,
                                                 void* __restrict__ Cout,
                                                 const float* __restrict__ bias,
                                                 const float* __restrict__ res,
                                                 int M, int N, int K){
  __shared__ unsigned short sA[128*64];
  __shared__ unsigned short sB[128*64];
  int tid = threadIdx.x;
  int m0 = blockIdx.x*128, n0 = blockIdx.y*128;
  int wid = tid>>6, lane = tid&63;
  int wm = (wid>>1)*64, wn = (wid&1)*64;
  int l16 = lane&15, quad = lane>>4;
  int qa0 = (quad     ^ (l16&7))*8;
  int qa1 = ((quad+4) ^ (l16&7))*8;

  f32x4 acc[4][4] = {};
  for (int k0=0; k0<K; k0+=64){
    #pragma unroll
    for (int i=0;i<4;i++){
      int t = i*256 + tid;                         // [0,1024)
      int row = t>>3;
      int kc = ((t&7) ^ (row&7))*8;
      int wb = i*256 + (tid & ~63);
      g2l16(A  + (size_t)(m0+row)*K + k0 + kc, sA + wb*8);
      g2l16(BT + (size_t)(n0+row)*K + k0 + kc, sB + wb*8);
    }
    __syncthreads();
    #pragma unroll
    for (int kk=0;kk<2;kk++){
      int qa = kk ? qa1 : qa0;
      short8 af[4], bf[4];
      #pragma unroll
      for (int mi=0;mi<4;mi++) af[mi] = *(const short8*)(sA + (wm+mi*16+l16)*64 + qa);
      #pragma unroll
      for (int ni=0;ni<4;ni++) bf[ni] = *(const short8*)(sB + (wn+ni*16+l16)*64 + qa);
      #pragma unroll
      for (int mi=0;mi<4;mi++)
        #pragma unroll
        for (int ni=0;ni<4;ni++)
          acc[mi][ni] = __builtin_amdgcn_mfma_f32_16x16x32_bf16(af[mi], bf[ni], acc[mi][ni], 0,0,0);
    }
    __syncthreads();
  }
  #pragma unroll
  for (int mi=0;mi<4;mi++)
    #pragma unroll
    for (int ni=0;ni<4;ni++){
      int col = n0 + wn + ni*16 + l16;
      float bval = 0.f;
      if constexpr (BIAS) bval = bias[col];
      #pragma unroll
      for (int r=0;r<4;r++){
        int row = m0 + wm + mi*16 + quad*4 + r;
        float v = acc[mi][ni][r] + bval;
        if constexpr (GELU) v = gelu_exact(v);
        if constexpr (RES)  v += res[(size_t)row*N + col];
        if constexpr (OUTBF) ((unsigned short*)Cout)[(size_t)row*N + col] = f32_to_bf16(v);
        else                 ((float*)Cout)[(size_t)row*N + col] = v;
      }
    }
}

// 128x64-tile, BK=64 variant for N=1024 outputs (512 blocks -> 2/CU).
template<bool BIAS, bool RES, bool OUTBF>
__global__ __launch_bounds__(256,2) void gemm_bt_n64(const unsigned short* __restrict__ A,
                                                     const unsigned short* __restrict__ BT,
                                                     void* __restrict__ Cout,
                                                     const float* __restrict__ bias,
                                                     const float* __restrict__ res,
                                                     int M, int N, int K){
  __shared__ unsigned short sA[128*64];
  __shared__ unsigned short sB[64*64];
  int tid = threadIdx.x;
  int m0 = blockIdx.x*128, n0 = blockIdx.y*64;
  int wid = tid>>6, lane = tid&63;
  int wm = (wid>>1)*64, wn = (wid&1)*32;
  int l16 = lane&15, quad = lane>>4;
  int qa0 = (quad     ^ (l16&7))*8;   // k-slice 0 read chunk
  int qa1 = ((quad+4) ^ (l16&7))*8;   // k-slice 1 read chunk

  f32x4 acc[4][2] = {};
  for (int k0=0; k0<K; k0+=64){
    #pragma unroll
    for (int i=0;i<4;i++){
      int t = i*256 + tid;                         // [0,1024)
      int row = t>>3;
      int kc = ((t&7) ^ (row&7))*8;
      int wb = i*256 + (tid & ~63);
      g2l16(A + (size_t)(m0+row)*K + k0 + kc, sA + wb*8);
    }
    #pragma unroll
    for (int i=0;i<2;i++){
      int t = i*256 + tid;                         // [0,512)
      int row = t>>3;
      int kc = ((t&7) ^ (row&7))*8;
      int wb = i*256 + (tid & ~63);
      g2l16(BT + (size_t)(n0+row)*K + k0 + kc, sB + wb*8);
    }
    __syncthreads();
    #pragma unroll
    for (int kk=0;kk<2;kk++){
      int qa = kk ? qa1 : qa0;
      short8 af[4], bf[2];
      #pragma unroll
      for (int mi=0;mi<4;mi++) af[mi] = *(const short8*)(sA + (wm+mi*16+l16)*64 + qa);
      #pragma unroll
      for (int ni=0;ni<2;ni++) bf[ni] = *(const short8*)(sB + (wn+ni*16+l16)*64 + qa);
      #pragma unroll
      for (int mi=0;mi<4;mi++)
        #pragma unroll
        for (int ni=0;ni<2;ni++)
          acc[mi][ni] = __builtin_amdgcn_mfma_f32_16x16x32_bf16(af[mi], bf[kk==0?ni:ni], acc[mi][ni], 0,0,0),
          acc[mi][ni] = acc[mi][ni];
    }
    __syncthreads();
  }
  #pragma unroll
  for (int mi=0;mi<4;mi++)
    #pragma unroll
    for (int ni=0;ni<2;ni++){
      int col = n0 + wn + ni*16 + l16;
      float bval = 0.f;
      if constexpr (BIAS) bval = bias[col];
      #pragma unroll
      for (int r=0;r<4;r++){
        int row = m0 + wm + mi*16 + quad*4 + r;
        float v = acc[mi][ni][r] + bval;
        if constexpr (RES)  v += res[(size_t)row*N + col];
        if constexpr (OUTBF) ((unsigned short*)Cout)[(size_t)row*N + col] = f32_to_bf16(v);
        else                 ((float*)Cout)[(size_t)row*N + col] = v;
      }
    }
}

// ------------------------------------------------------------- attention
// grid (33, 32): x<32 -> sparse-gather flash attention for q-tile 31-x;
// x==32 -> dense last-row (row T-1) attention, vectorized two-pass softmax.
__global__ __launch_bounds__(256,4) void attn_kernel(const unsigned short* __restrict__ qkv,
                                                     const int* __restrict__ cols,
                                                     const int* __restrict__ ncols,
                                                     const unsigned int* __restrict__ rmask,
                                                     unsigned short* __restrict__ out){
  __shared__ __align__(16) char smem[36864];
  int bh = blockIdx.y;                // 0..31
  int b = bh >> 4, h = bh & 15;
  int tid = threadIdx.x, wid = tid>>6, lane = tid&63;
  const int RS = 3072;
  const size_t base = (size_t)b * T_SEQ * RS;

  if (blockIdx.x == 32){
    // ---------------- dense last row ----------------
    float* sS  = (float*)smem;                      // 2048 f32
    float* sOr = (float*)(smem + 8192);             // 32 x 65 f32 (padded)
    float* sRed= (float*)(smem + 16512);            // 8 f32
    unsigned short* sQ = (unsigned short*)(smem + 16544); // 64 bf16

    if (tid < 8)
      ((uint4*)sQ)[tid] = *(const uint4*)(qkv + base + (size_t)(T_SEQ-1)*RS + h*64 + tid*8);
    __syncthreads();
    unsigned short q16[64];
    #pragma unroll
    for (int c=0;c<8;c++) *(uint4*)(q16 + c*8) = ((const uint4*)sQ)[c];

    float lmax = -1e30f;
    #pragma unroll
    for (int i=0;i<8;i++){
      int k = tid + 256*i;
      const unsigned short* kp = qkv + base + (size_t)k*RS + 1024 + h*64;
      float acc = 0.f;
      #pragma unroll
      for (int c=0;c<8;c++){
        unsigned short kk[8];
        *(uint4*)kk = *(const uint4*)(kp + c*8);
        #pragma unroll
        for (int j=0;j<8;j++) acc += bf16_to_f32(q16[c*8+j])*bf16_to_f32(kk[j]);
      }
      float sv = acc * 0.125f;
      sS[k] = sv;
      lmax = fmaxf(lmax, sv);
    }
    #pragma unroll
    for (int d=1; d<64; d<<=1) lmax = fmaxf(lmax, __shfl_xor(lmax, d, 64));
    if (lane == 0) sRed[wid] = lmax;
    __syncthreads();
    float m = fmaxf(fmaxf(sRed[0],sRed[1]), fmaxf(sRed[2],sRed[3]));
    float lsum = 0.f;
    #pragma unroll
    for (int i=0;i<8;i++){
      int k = tid + 256*i;
      float p = __expf(sS[k] - m);
      sS[k] = p;
      lsum += p;
    }
    #pragma unroll
    for (int d=1; d<64; d<<=1) lsum += __shfl_xor(lsum, d, 64);
    if (lane == 0) sRed[4+wid] = lsum;
    __syncthreads();
    float l = sRed[4]+sRed[5]+sRed[6]+sRed[7];

    int dg = tid & 7, kl = tid >> 3;
    float o8[8] = {};
    const unsigned short* vbase = qkv + base + 2048 + h*64 + dg*8;
    #pragma unroll 4
    for (int i=0;i<64;i++){
      int k = kl + 32*i;
      float p = sS[k];
      unsigned short vv[8];
      *(uint4*)vv = *(const uint4*)(vbase + (size_t)k*RS);
      #pragma unroll
      for (int j=0;j<8;j++) o8[j] += p * bf16_to_f32(vv[j]);
    }
    #pragma unroll
    for (int j=0;j<8;j++) sOr[kl*65 + dg*8 + j] = o8[j];
    __syncthreads();
    if (tid < 64){
      float s = 0.f;
      #pragma unroll
      for (int k2=0;k2<32;k2++) s += sOr[k2*65 + tid];
      out[(size_t)(b*T_SEQ + T_SEQ-1)*1024 + h*64 + tid] = f32_to_bf16(s / l);
    }
    return;
  }

  // ---------------- sparse q-tiles ----------------
  unsigned short* sK  = (unsigned short*)smem;            // [64][72]
  unsigned short* sVt = (unsigned short*)(smem +  9216);  // [64][72]
  unsigned short* sX  = (unsigned short*)(smem + 18432);  // [64][72]
  unsigned short* sP  = (unsigned short*)(smem + 27648);  // [4][16][72]

  int qt = 31 - blockIdx.x;
  int l16 = lane&15, quad = lane>>4;
  int q0 = qt*64;

  const int* gcols = cols + qt*2048;
  int niter = ncols[qt] >> 6;

  int qrow = q0 + wid*16 + l16;
  const unsigned short* qptr = qkv + base + (size_t)qrow*RS + h*64;
  short8 qf0 = *(const short8*)(qptr + quad*8);
  short8 qf1 = *(const short8*)(qptr + 32 + quad*8);

  f32x4 o[4] = {};
  float m_i[4], l_i[4];
  #pragma unroll
  for (int r=0;r<4;r++){ m_i[r] = -1e30f; l_i[r] = 0.f; }

  int krow0 = tid>>3, krow1 = 32 + (tid>>3), dc = (tid&7)*8;
  int c0n = gcols[krow0], c1n = gcols[krow1];

  for (int kt=0; kt<niter; ++kt){
    int c0 = c0n < 0 ? 0 : c0n;
    int c1 = c1n < 0 ? 0 : c1n;
    const unsigned short* p0 = qkv + base + (size_t)c0*RS + 1024 + h*64 + dc;
    const unsigned short* p1 = qkv + base + (size_t)c1*RS + 1024 + h*64 + dc;
    uint4 k0 = *(const uint4*)p0;
    uint4 k1 = *(const uint4*)p1;
    uint4 v0 = *(const uint4*)(p0 + 1024);
    uint4 v1 = *(const uint4*)(p1 + 1024);
    if (kt+1 < niter){
      c0n = gcols[(kt+1)*64 + krow0];
      c1n = gcols[(kt+1)*64 + krow1];
    }
    __syncthreads();                       // prev iter's LDS readers done
    *(uint4*)(sK + krow0*72 + dc) = k0;
    *(uint4*)(sK + krow1*72 + dc) = k1;
    *(uint4*)(sX + krow0*72 + dc) = v0;
    *(uint4*)(sX + krow1*72 + dc) = v1;
    __syncthreads();                       // sK/sX visible

    // transpose sX -> sVt (krow lane-fast => conflict-free)
    #pragma unroll
    for (int pass=0; pass<2; ++pass){
      int dg = pass*4 + wid;
      unsigned short v8[8];
      *(uint4*)v8 = *(const uint4*)(sX + lane*72 + dg*8);
      #pragma unroll
      for (int j=0;j<8;j++) sVt[(dg*8+j)*72 + lane] = v8[j];
    }

    // S = Q @ K^T
    f32x4 s[4];
    #pragma unroll
    for (int nt=0;nt<4;nt++){
      f32x4 z = {};
      short8 kb0 = *(const short8*)(sK + (nt*16+l16)*72 + quad*8);
      short8 kb1 = *(const short8*)(sK + (nt*16+l16)*72 + 32 + quad*8);
      z = __builtin_amdgcn_mfma_f32_16x16x32_bf16(qf0, kb0, z, 0,0,0);
      z = __builtin_amdgcn_mfma_f32_16x16x32_bf16(qf1, kb1, z, 0,0,0);
      s[nt] = z;
    }

    // mask (remapped bits) + scale
    float rowmax[4];
    #pragma unroll
    for (int r=0;r<4;r++){
      int rowin = wid*16 + quad*4 + r;
      const unsigned int* mrow = rmask + (size_t)(qt*64+rowin)*64 + kt*2;
      unsigned long long m64 = (unsigned long long)mrow[0] |
                               ((unsigned long long)mrow[1] << 32);
      float rm = -1e30f;
      #pragma unroll
      for (int nt=0;nt<4;nt++){
        int c6 = nt*16 + l16;
        bool ok = (m64 >> c6) & 1ull;
        float v = ok ? s[nt][r]*0.125f : -1e30f;
        s[nt][r] = v;
        rm = fmaxf(rm, v);
      }
      rowmax[r] = rm;
    }
    #pragma unroll
    for (int r=0;r<4;r++){
      float v = rowmax[r];
      #pragma unroll
      for (int d=1; d<16; d<<=1) v = fmaxf(v, __shfl_xor(v,d,64));
      rowmax[r] = v;
    }
    float alpha[4];
    #pragma unroll
    for (int r=0;r<4;r++){
      float mnew = fmaxf(m_i[r], rowmax[r]);
      alpha[r] = __expf(m_i[r] - mnew);
      m_i[r] = mnew;
    }
    #pragma unroll
    for (int nt=0;nt<4;nt++)
      #pragma unroll
      for (int r=0;r<4;r++)
        s[nt][r] = __expf(s[nt][r] - m_i[r]);
    #pragma unroll
    for (int r=0;r<4;r++){
      float v = s[0][r]+s[1][r]+s[2][r]+s[3][r];
      #pragma unroll
      for (int d=1; d<16; d<<=1) v += __shfl_xor(v,d,64);
      l_i[r] = l_i[r]*alpha[r] + v;
    }
    // P: C-layout -> per-wave LDS -> A-layout (same-wave RAW, no barrier)
    unsigned short* sPw = sP + wid*16*72;
    #pragma unroll
    for (int nt=0;nt<4;nt++)
      #pragma unroll
      for (int r=0;r<4;r++)
        sPw[(quad*4+r)*72 + nt*16 + l16] = f32_to_bf16(s[nt][r]);
    short8 p0f = *(const short8*)(sPw + l16*72 + quad*8);
    short8 p1f = *(const short8*)(sPw + l16*72 + 32 + quad*8);
    #pragma unroll
    for (int nt=0;nt<4;nt++)
      #pragma unroll
      for (int r=0;r<4;r++)
        o[nt][r] *= alpha[r];
    __syncthreads();                       // sVt complete
    #pragma unroll
    for (int nt=0;nt<4;nt++){
      short8 vb0 = *(const short8*)(sVt + (nt*16+l16)*72 + quad*8);
      short8 vb1 = *(const short8*)(sVt + (nt*16+l16)*72 + 32 + quad*8);
      o[nt] = __builtin_amdgcn_mfma_f32_16x16x32_bf16(p0f, vb0, o[nt], 0,0,0);
      o[nt] = __builtin_amdgcn_mfma_f32_16x16x32_bf16(p1f, vb1, o[nt], 0,0,0);
    }
  }
  #pragma unroll
  for (int nt=0;nt<4;nt++)
    #pragma unroll
    for (int r=0;r<4;r++){
      int row = q0 + wid*16 + quad*4 + r;
      if (row == T_SEQ-1) continue;        // owned by lastrow block (race!)
      int col = h*64 + nt*16 + l16;
      out[(size_t)(b*T_SEQ + row)*1024 + col] = f32_to_bf16(o[nt][r] / l_i[r]);
    }
}

// ---------------------------------------------------------------- launch
extern "C" void kernel_launch(void* const* d_in, const int* in_sizes, int n_in,
                              void* d_out, int out_size, void* d_ws, size_t ws_size,
                              hipStream_t stream) {
  const float* x     = (const float*)d_in[0];
  const unsigned char* mask = (const unsigned char*)d_in[1];
  const float* ln1_g = (const float*)d_in[2];
  const float* ln1_b = (const float*)d_in[3];
  const float* ln2_g = (const float*)d_in[4];
  const float* ln2_b = (const float*)d_in[5];
  const float* Wq = (const float*)d_in[6];
  const float* Wk = (const float*)d_in[7];
  const float* Wv = (const float*)d_in[8];
  const float* Wo = (const float*)d_in[9];
  const float* bo = (const float*)d_in[10];
  const float* W1 = (const float*)d_in[11];
  const float* b1 = (const float*)d_in[12];
  const float* W2 = (const float*)d_in[13];
  const float* b2 = (const float*)d_in[14];
  float* out = (float*)d_out;

  char* ws = (char*)d_ws;
  unsigned short* wqkvT = (unsigned short*)(ws);              // 3072x1024 bf16
  unsigned short* woT   = (unsigned short*)(ws + 6291456);    // 1024x1024
  unsigned short* w1T   = (unsigned short*)(ws + 8388608);    // 4096x1024
  unsigned short* w2T   = (unsigned short*)(ws + 16777216);   // 1024x4096
  unsigned short* h_bf  = (unsigned short*)(ws + 25165824);   // 4096x1024 (reused as h2)
  unsigned short* qkv   = (unsigned short*)(ws + 33554432);   // 4096x3072
  unsigned short* aout  = (unsigned short*)(ws + 58720256);   // 4096x1024
  int*            cols  = (int*)(ws + 67108864);              // 32x2048 ints (256 KB)
  int*            ncols = (int*)(ws + 67371008);              // 32 ints
  unsigned int*   rmask = (unsigned int*)(ws + 67371136);     // 32x64x64 words (512 KB)
  unsigned short* ff1   = qkv;                                // reuse: 4096x4096

  prep_fused<<<16416,256,0,stream>>>(mask, cols, ncols, rmask,
                                     Wq, Wk, Wv, Wo, W1, W2,
                                     wqkvT, woT, w1T, w2T,
                                     x, ln1_g, ln1_b, h_bf);

  gemm_bt<false,false,false,true><<<dim3(32,24),256,0,stream>>>(h_bf, wqkvT, qkv, nullptr, nullptr, 4096, 3072, 1024);
  attn_kernel<<<dim3(33,32),256,0,stream>>>(qkv, cols, ncols, rmask, aout);
  gemm_bt_n64<true,true,false><<<dim3(32,16),256,0,stream>>>(aout, woT, out, bo, x, 4096, 1024, 1024);
  ln_kernel<<<4096,256,0,stream>>>(out, ln2_g, ln2_b, h_bf);
  gemm_bt<true,true,false,true><<<dim3(32,32),256,0,stream>>>(h_bf, w1T, ff1, b1, nullptr, 4096, 4096, 1024);
  gemm_bt_n64<true,true,false><<<dim3(32,16),256,0,stream>>>(ff1, w2T, out, b2, out, 4096, 1024, 4096);
}